// Round 1
// baseline (204.011 us; speedup 1.0000x reference)
//
#include <hip/hip_runtime.h>
#include <stdint.h>

#define N_V   4096
#define T_PER 4
#define NT    16384
#define D_K   256
#define SCALE 10.0f   // 1/temperature

typedef __bf16 bf16x8 __attribute__((ext_vector_type(8)));
typedef float  f32x4  __attribute__((ext_vector_type(4)));

__device__ __forceinline__ unsigned short f2bf(float f) {
  uint32_t u = __float_as_uint(f);
  u = (u + 0x7fffu + ((u >> 16) & 1u)) >> 16;   // RNE
  return (unsigned short)u;
}

// ---------------- A1: fp32 -> bf16 (V scaled by 10 so scores come out pre-scaled) ---------------
__global__ void k_convert(const float* __restrict__ v, const float* __restrict__ t,
                          unsigned short* __restrict__ Abf, unsigned short* __restrict__ Bbf) {
  int idx = blockIdx.x * blockDim.x + threadIdx.x;
  const int NV4 = N_V * D_K / 4;
  if (idx < NV4) {
    float4 x = ((const float4*)v)[idx];
    ushort4 o;
    o.x = f2bf(x.x * SCALE); o.y = f2bf(x.y * SCALE);
    o.z = f2bf(x.z * SCALE); o.w = f2bf(x.w * SCALE);
    ((ushort4*)Abf)[idx] = o;
  } else {
    int j = idx - NV4;
    float4 x = ((const float4*)t)[j];
    ushort4 o;
    o.x = f2bf(x.x); o.y = f2bf(x.y); o.z = f2bf(x.z); o.w = f2bf(x.w);
    ((ushort4*)Bbf)[j] = o;
  }
}

// ---------------- A2: diagonal dots (fp32-exact) -> thresholds + nominator ---------------
__global__ void k_thr(const float* __restrict__ v, const float* __restrict__ t,
                      float* __restrict__ thr, float* __restrict__ nom) {
  int i = blockIdx.x;
  int l = threadIdx.x;                       // one wave per video
  float4 a = ((const float4*)(v + (size_t)i * D_K))[l];
  float tv[T_PER];
#pragma unroll
  for (int tt = 0; tt < T_PER; ++tt) {
    float4 b = ((const float4*)(t + (size_t)(i * T_PER + tt) * D_K))[l];
    float d = a.x * b.x + a.y * b.y + a.z * b.z + a.w * b.w;
#pragma unroll
    for (int s = 1; s < 64; s <<= 1) d += __shfl_xor(d, s);
    tv[tt] = d * SCALE;
  }
  if (l == 0) {
    ((float4*)thr)[i] = make_float4(tv[0], tv[1], tv[2], tv[3]);
    float m = fmaxf(fmaxf(tv[0], tv[1]), fmaxf(tv[2], tv[3]));
    float e = __expf(tv[0] - m) + __expf(tv[1] - m) + __expf(tv[2] - m) + __expf(tv[3] - m);
    nom[i] = m + __logf(e);
  }
}

// ---------------- B: fused bf16 MFMA GEMM + LSE/rank-count epilogue ---------------
__device__ __forceinline__ void gld16(const void* g, void* l) {
  __builtin_amdgcn_global_load_lds((const __attribute__((address_space(1))) void*)g,
                                   (__attribute__((address_space(3))) void*)l,
                                   16, 0, 0);
}

__global__ __launch_bounds__(256) void k_gemm(
    const unsigned short* __restrict__ Abf, const unsigned short* __restrict__ Bbf,
    const float* __restrict__ thr,
    float* __restrict__ pmax, float* __restrict__ psum, uint32_t* __restrict__ pcnt,
    float* __restrict__ cmax, float* __restrict__ csum) {
  // LDS tiles: [128 rows][64 k] bf16, stored in 8-row groups of 1024B with chunk-XOR swizzle
  // (global_load_lds forces base + lane*16 placement; swizzle keeps ds_read_b128 conflict-free)
  __shared__ __align__(16) unsigned short As[128 * 64];
  __shared__ __align__(16) unsigned short Bs[128 * 64];
  const int ct = blockIdx.x, rt = blockIdx.y;
  const int row0 = rt * 128, col0 = ct * 128;
  const int tid = threadIdx.x;
  const int l = tid & 63, w = tid >> 6;
  const int quad = l >> 4, nl = l & 15;
  const int wr0 = (w >> 1) * 64, wc0 = (w & 1) * 64;

  f32x4 acc[4][4];
#pragma unroll
  for (int i = 0; i < 4; ++i)
#pragma unroll
    for (int j = 0; j < 4; ++j) acc[i][j] = {0.f, 0.f, 0.f, 0.f};

  const int lr = l >> 3;            // row within 8-row group
  const int lc = (l & 7) ^ lr;      // swizzled global chunk index

  for (int k0 = 0; k0 < D_K; k0 += 64) {
    if (k0) __syncthreads();
#pragma unroll
    for (int it = 0; it < 4; ++it) {
      int g = w * 4 + it;           // 16 groups of 8 rows
      const unsigned short* ga = Abf + (size_t)(row0 + g * 8 + lr) * D_K + k0 + lc * 8;
      gld16(ga, (char*)As + g * 1024);
      const unsigned short* gb = Bbf + (size_t)(col0 + g * 8 + lr) * D_K + k0 + lc * 8;
      gld16(gb, (char*)Bs + g * 1024);
    }
    __syncthreads();
#pragma unroll
    for (int kk = 0; kk < 64; kk += 32) {
      const int cb = (kk >> 3) + quad;
      bf16x8 af[4], bv[4];
#pragma unroll
      for (int i = 0; i < 4; ++i) {
        int r = wr0 + i * 16 + nl;
        af[i] = *(const bf16x8*)((const char*)As + r * 128 + ((cb ^ (r & 7)) << 4));
      }
#pragma unroll
      for (int j = 0; j < 4; ++j) {
        int n = wc0 + j * 16 + nl;
        bv[j] = *(const bf16x8*)((const char*)Bs + n * 128 + ((cb ^ (n & 7)) << 4));
      }
#pragma unroll
      for (int i = 0; i < 4; ++i)
#pragma unroll
        for (int j = 0; j < 4; ++j)
          acc[i][j] = __builtin_amdgcn_mfma_f32_16x16x32_bf16(af[i], bv[j], acc[i][j], 0, 0, 0);
    }
  }

  // ---- epilogue: stage thresholds, then row/col online-LSE partials + rank counts ----
  __syncthreads();
  float4* thrS = (float4*)As;                 // reuse LDS (2 KB)
  if (tid < 128) thrS[tid] = ((const float4*)thr)[row0 + tid];
  __syncthreads();

  // row partials: each (i,reg) is one row; its 64 tile-cols live on 16 lanes x 4 j
#pragma unroll
  for (int i = 0; i < 4; ++i) {
#pragma unroll
    for (int reg = 0; reg < 4; ++reg) {
      int rl = wr0 + i * 16 + quad * 4 + reg;
      float s0 = acc[i][0][reg], s1 = acc[i][1][reg], s2 = acc[i][2][reg], s3 = acc[i][3][reg];
      float m = fmaxf(fmaxf(s0, s1), fmaxf(s2, s3));
#pragma unroll
      for (int d = 1; d < 16; d <<= 1) m = fmaxf(m, __shfl_xor(m, d));
      float e = __expf(s0 - m) + __expf(s1 - m) + __expf(s2 - m) + __expf(s3 - m);
      float4 th = thrS[rl];
      uint32_t c =  (uint32_t)((s0 > th.x) + (s1 > th.x) + (s2 > th.x) + (s3 > th.x));
      c |= (uint32_t)((s0 > th.y) + (s1 > th.y) + (s2 > th.y) + (s3 > th.y)) << 8;
      c |= (uint32_t)((s0 > th.z) + (s1 > th.z) + (s2 > th.z) + (s3 > th.z)) << 16;
      c |= (uint32_t)((s0 > th.w) + (s1 > th.w) + (s2 > th.w) + (s3 > th.w)) << 24;
#pragma unroll
      for (int d = 1; d < 16; d <<= 1) { e += __shfl_xor(e, d); c += __shfl_xor(c, d); }
      if (nl == 0) {
        size_t idx = (size_t)(row0 + rl) * 256 + (ct * 2 + (w & 1));
        pmax[idx] = m; psum[idx] = e; pcnt[idx] = c;
      }
    }
  }

  // col partials: each (j,nl) is one col; its 64 tile-rows live on 4 quads x 16 (i,reg)
#pragma unroll
  for (int j = 0; j < 4; ++j) {
    float m = -3.0e38f;
#pragma unroll
    for (int i = 0; i < 4; ++i)
#pragma unroll
      for (int reg = 0; reg < 4; ++reg) m = fmaxf(m, acc[i][j][reg]);
    m = fmaxf(m, __shfl_xor(m, 16));
    m = fmaxf(m, __shfl_xor(m, 32));
    float e = 0.f;
#pragma unroll
    for (int i = 0; i < 4; ++i)
#pragma unroll
      for (int reg = 0; reg < 4; ++reg) e += __expf(acc[i][j][reg] - m);
    e += __shfl_xor(e, 16);
    e += __shfl_xor(e, 32);
    if (quad == 0) {
      size_t idx = (size_t)(col0 + wc0 + j * 16 + nl) * 64 + (rt * 2 + (w >> 1));
      cmax[idx] = m; csum[idx] = e;
    }
  }
}

// ---------------- C: reduce 256 row-partials per row ---------------
__global__ void k_rowred(const float* __restrict__ pmax, const float* __restrict__ psum,
                         const uint32_t* __restrict__ pcnt,
                         float* __restrict__ rowm, float* __restrict__ rows_,
                         uint4* __restrict__ rcnt) {
  int row = blockIdx.x, l = threadIdx.x;   // one wave, 4 parts/lane
  float4 pm = ((const float4*)(pmax + (size_t)row * 256))[l];
  float4 ps = ((const float4*)(psum + (size_t)row * 256))[l];
  uint4  pc = ((const uint4*)(pcnt + (size_t)row * 256))[l];
  float m = fmaxf(fmaxf(pm.x, pm.y), fmaxf(pm.z, pm.w));
#pragma unroll
  for (int d = 1; d < 64; d <<= 1) m = fmaxf(m, __shfl_xor(m, d));
  float e = ps.x * __expf(pm.x - m) + ps.y * __expf(pm.y - m)
          + ps.z * __expf(pm.z - m) + ps.w * __expf(pm.w - m);
  uint32_t parts[4] = {pc.x, pc.y, pc.z, pc.w};
  uint32_t c0 = 0, c1 = 0, c2 = 0, c3 = 0;
#pragma unroll
  for (int k = 0; k < 4; ++k) {
    c0 += parts[k] & 0xffu;         c1 += (parts[k] >> 8) & 0xffu;
    c2 += (parts[k] >> 16) & 0xffu; c3 += parts[k] >> 24;
  }
#pragma unroll
  for (int d = 1; d < 64; d <<= 1) {
    e += __shfl_xor(e, d);
    c0 += __shfl_xor(c0, d); c1 += __shfl_xor(c1, d);
    c2 += __shfl_xor(c2, d); c3 += __shfl_xor(c3, d);
  }
  if (l == 0) { rowm[row] = m; rows_[row] = e; rcnt[row] = make_uint4(c0, c1, c2, c3); }
}

// ---------------- D: reduce 64 col-partials per column ---------------
__global__ void k_colred(const float* __restrict__ cmax, const float* __restrict__ csum,
                         float* __restrict__ colm, float* __restrict__ cols) {
  int col = blockIdx.x, l = threadIdx.x;
  float m = cmax[(size_t)col * 64 + l];
  float s = csum[(size_t)col * 64 + l];
  float M = m;
#pragma unroll
  for (int d = 1; d < 64; d <<= 1) M = fmaxf(M, __shfl_xor(M, d));
  float e = s * __expf(m - M);
#pragma unroll
  for (int d = 1; d < 64; d <<= 1) e += __shfl_xor(e, d);
  if (l == 0) { colm[col] = M; cols[col] = e; }
}

// ---------------- E: combine, loss + metrics, means ---------------
__global__ void k_final(const float* __restrict__ rowm, const float* __restrict__ rows_,
                        const uint4* __restrict__ rcnt, const float* __restrict__ nom,
                        const float* __restrict__ colm, const float* __restrict__ cols,
                        float* __restrict__ out) {
  int tid = threadIdx.x;
  float ll = 0, r1 = 0, r5 = 0, r10 = 0, ar = 0;
  for (int r = tid; r < N_V; r += 256) {
    float M = rowm[r], S = rows_[r];
    float4 cm = ((const float4*)colm)[r];
    float4 cs = ((const float4*)cols)[r];
    float Mp = fmaxf(M, fmaxf(fmaxf(cm.x, cm.y), fmaxf(cm.z, cm.w)));
    float tot = S * __expf(M - Mp)
              + cs.x * __expf(cm.x - Mp) + cs.y * __expf(cm.y - Mp)
              + cs.z * __expf(cm.z - Mp) + cs.w * __expf(cm.w - Mp);
    ll += (Mp + __logf(tot)) - nom[r];
    uint4 c = rcnt[r];
    ar  += (float)(c.x + c.y + c.z + c.w) * 0.25f;
    r1  += (float)((c.x < 1) + (c.y < 1) + (c.z < 1) + (c.w < 1)) * 0.25f;
    r5  += (float)((c.x < 5) + (c.y < 5) + (c.z < 5) + (c.w < 5)) * 0.25f;
    r10 += (float)((c.x < 10) + (c.y < 10) + (c.z < 10) + (c.w < 10)) * 0.25f;
  }
  __shared__ float red[4];
  float vals[5] = {ll, r1, r5, r10, ar};
  int l = tid & 63, w = tid >> 6;
#pragma unroll
  for (int k = 0; k < 5; ++k) {
    float v = vals[k];
#pragma unroll
    for (int d = 1; d < 64; d <<= 1) v += __shfl_xor(v, d);
    if (l == 0) red[w] = v;
    __syncthreads();
    if (tid == 0) out[k] = (red[0] + red[1] + red[2] + red[3]) * (1.0f / N_V);
    __syncthreads();
  }
}

extern "C" void kernel_launch(void* const* d_in, const int* in_sizes, int n_in,
                              void* d_out, int out_size, void* d_ws, size_t ws_size,
                              hipStream_t stream) {
  const float* v = (const float*)d_in[0];
  const float* t = (const float*)d_in[1];
  char* p = (char*)d_ws;
  unsigned short* Abf = (unsigned short*)p; p += (size_t)N_V * D_K * 2;
  unsigned short* Bbf = (unsigned short*)p; p += (size_t)NT * D_K * 2;
  float* thr  = (float*)p;    p += (size_t)N_V * 4 * 4;
  float* nom  = (float*)p;    p += (size_t)N_V * 4;
  float* pmax = (float*)p;    p += (size_t)N_V * 256 * 4;
  float* psum = (float*)p;    p += (size_t)N_V * 256 * 4;
  uint32_t* pcnt = (uint32_t*)p; p += (size_t)N_V * 256 * 4;
  float* cmaxp = (float*)p;   p += (size_t)NT * 64 * 4;
  float* csump = (float*)p;   p += (size_t)NT * 64 * 4;
  float* rowm = (float*)p;    p += (size_t)N_V * 4;
  float* rows_ = (float*)p;   p += (size_t)N_V * 4;
  uint4* rcnt = (uint4*)p;    p += (size_t)N_V * 16;
  float* colm = (float*)p;    p += (size_t)NT * 4;
  float* cols = (float*)p;    p += (size_t)NT * 4;
  // total ws: ~30.4 MB

  k_convert<<<(N_V * D_K / 4 + NT * D_K / 4) / 256, 256, 0, stream>>>(v, t, Abf, Bbf);
  k_thr<<<N_V, 64, 0, stream>>>(v, t, thr, nom);
  dim3 g(NT / 128, N_V / 128);
  k_gemm<<<g, 256, 0, stream>>>(Abf, Bbf, thr, pmax, psum, pcnt, cmaxp, csump);
  k_rowred<<<N_V, 64, 0, stream>>>(pmax, psum, pcnt, rowm, rows_, rcnt);
  k_colred<<<NT, 64, 0, stream>>>(cmaxp, csump, colm, cols);
  k_final<<<1, 256, 0, stream>>>(rowm, rows_, rcnt, nom, colm, cols, (float*)d_out);
}

// Round 4
// 201.670 us; speedup vs baseline: 1.0116x; 1.0116x over previous
//
#include <hip/hip_runtime.h>
#include <stdint.h>

#define N_V   4096
#define T_PER 4
#define NT    16384
#define D_K   256
#define SCALE 10.0f   // 1/temperature

typedef __bf16 bf16x8 __attribute__((ext_vector_type(8)));
typedef float  f32x4  __attribute__((ext_vector_type(4)));

__device__ __forceinline__ unsigned short f2bf(float f) {
  uint32_t u = __float_as_uint(f);
  u = (u + 0x7fffu + ((u >> 16) & 1u)) >> 16;   // RNE
  return (unsigned short)u;
}

// ---------------- A1: fp32 -> bf16 (V scaled by 10 so scores come out pre-scaled) ----------
__global__ void k_convert(const float* __restrict__ v, const float* __restrict__ t,
                          unsigned short* __restrict__ Abf, unsigned short* __restrict__ Bbf) {
  int idx = blockIdx.x * blockDim.x + threadIdx.x;
  const int NV4 = N_V * D_K / 4;
  if (idx < NV4) {
    float4 x = ((const float4*)v)[idx];
    ushort4 o;
    o.x = f2bf(x.x * SCALE); o.y = f2bf(x.y * SCALE);
    o.z = f2bf(x.z * SCALE); o.w = f2bf(x.w * SCALE);
    ((ushort4*)Abf)[idx] = o;
  } else {
    int j = idx - NV4;
    float4 x = ((const float4*)t)[j];
    ushort4 o;
    o.x = f2bf(x.x); o.y = f2bf(x.y); o.z = f2bf(x.z); o.w = f2bf(x.w);
    ((ushort4*)Bbf)[j] = o;
  }
}

// ---------------- A2: diagonal dots (fp32-exact) -> thresholds + nominator; zero d_out ------
__global__ void k_thr(const float* __restrict__ v, const float* __restrict__ t,
                      float* __restrict__ thr, float* __restrict__ nom,
                      float* __restrict__ out) {
  int i = blockIdx.x;
  int l = threadIdx.x;                       // one wave per video
  if (i == 0 && l < 5) out[l] = 0.0f;        // zero outputs for later atomicAdd
  float4 a = ((const float4*)(v + (size_t)i * D_K))[l];
  float tv[T_PER];
#pragma unroll
  for (int tt = 0; tt < T_PER; ++tt) {
    float4 b = ((const float4*)(t + (size_t)(i * T_PER + tt) * D_K))[l];
    float d = a.x * b.x + a.y * b.y + a.z * b.z + a.w * b.w;
#pragma unroll
    for (int s = 1; s < 64; s <<= 1) d += __shfl_xor(d, s);
    tv[tt] = d * SCALE;
  }
  if (l == 0) {
    ((float4*)thr)[i] = make_float4(tv[0], tv[1], tv[2], tv[3]);
    float m = fmaxf(fmaxf(tv[0], tv[1]), fmaxf(tv[2], tv[3]));
    float e = __expf(tv[0] - m) + __expf(tv[1] - m) + __expf(tv[2] - m) + __expf(tv[3] - m);
    nom[i] = m + __logf(e);
  }
}

// ---------------- B: fused bf16 MFMA GEMM + LSE/rank-count epilogue ------------------------
__device__ __forceinline__ void gld16(const void* g, void* l) {
  __builtin_amdgcn_global_load_lds((const __attribute__((address_space(1))) void*)g,
                                   (__attribute__((address_space(3))) void*)l,
                                   16, 0, 0);
}

__global__ __launch_bounds__(256) void k_gemm(
    const unsigned short* __restrict__ Abf, const unsigned short* __restrict__ Bbf,
    const float* __restrict__ thr,
    float* __restrict__ pmax, float* __restrict__ psum, uint32_t* __restrict__ pcnt,
    float* __restrict__ cmax, float* __restrict__ csum) {
  // Separately declared LDS objects — no overlap, no reuse, no type punning.
  __shared__ __align__(16) unsigned short As[128 * 64];
  __shared__ __align__(16) unsigned short Bs[128 * 64];
  __shared__ float4   thrS[128];
  __shared__ float    rowM[2][128];   // [col-half][row] per-row maxes  (underflow safety!)
  __shared__ float    rowE[2][128];   // [col-half][row] exp-sums rel. to own row max
  __shared__ uint32_t rowC[2][128];   // [col-half][row] packed counts
  __shared__ float    colM[2][128];   // [row-half][col] per-col maxes
  __shared__ float    colE[2][128];   // [row-half][col] exp-sums rel. to own col max

  const int ct = blockIdx.x, rt = blockIdx.y;
  const int row0 = rt * 128, col0 = ct * 128;
  const int tid = threadIdx.x;
  const int l = tid & 63, w = tid >> 6;
  const int quad = l >> 4, nl = l & 15;
  const int wr0 = (w >> 1) * 64, wc0 = (w & 1) * 64;

  f32x4 acc[4][4];
#pragma unroll
  for (int i = 0; i < 4; ++i)
#pragma unroll
    for (int j = 0; j < 4; ++j) acc[i][j] = {0.f, 0.f, 0.f, 0.f};

  const int lr = l >> 3;            // row within 8-row group
  const int lc = (l & 7) ^ lr;      // swizzled global chunk index

  for (int k0 = 0; k0 < D_K; k0 += 64) {
    if (k0) __syncthreads();
#pragma unroll
    for (int it = 0; it < 4; ++it) {
      int g = w * 4 + it;           // 16 groups of 8 rows
      const unsigned short* ga = Abf + (size_t)(row0 + g * 8 + lr) * D_K + k0 + lc * 8;
      gld16(ga, (char*)As + g * 1024);
      const unsigned short* gb = Bbf + (size_t)(col0 + g * 8 + lr) * D_K + k0 + lc * 8;
      gld16(gb, (char*)Bs + g * 1024);
    }
    __syncthreads();
#pragma unroll
    for (int kk = 0; kk < 64; kk += 32) {
      const int cb = (kk >> 3) + quad;
      bf16x8 af[4], bv[4];
#pragma unroll
      for (int i = 0; i < 4; ++i) {
        int r = wr0 + i * 16 + nl;
        af[i] = *(const bf16x8*)((const char*)As + r * 128 + ((cb ^ (r & 7)) << 4));
      }
#pragma unroll
      for (int j = 0; j < 4; ++j) {
        int n = wc0 + j * 16 + nl;
        bv[j] = *(const bf16x8*)((const char*)Bs + n * 128 + ((cb ^ (n & 7)) << 4));
      }
#pragma unroll
      for (int i = 0; i < 4; ++i)
#pragma unroll
        for (int j = 0; j < 4; ++j)
          acc[i][j] = __builtin_amdgcn_mfma_f32_16x16x32_bf16(af[i], bv[j], acc[i][j], 0, 0, 0);
    }
  }

  // ================= epilogue =================
  // C/D layout (16x16x32): col = nl (lane&15), row = quad*4 + reg.
  // Scores have sigma ~160: PER-ROW / PER-COL maxes are mandatory — a shared wave max
  // underflows exp() to 0 for weak rows (-> log(0) = -inf downstream).  [round-2/3 bug]
  if (tid < 128) thrS[tid] = ((const float4*)thr)[row0 + tid];
  __syncthreads();   // thrS visible; acc lives in registers

  // rank counts vs thresholds (raw scores), packed 4x8-bit per (row,lane)
  uint32_t cnt[4][4];
#pragma unroll
  for (int i = 0; i < 4; ++i)
#pragma unroll
    for (int r = 0; r < 4; ++r) {
      float4 th = thrS[wr0 + i * 16 + quad * 4 + r];
      uint32_t c = 0;
#pragma unroll
      for (int j = 0; j < 4; ++j) {
        float s = acc[i][j][r];
        c += (uint32_t)(s > th.x);
        c += (uint32_t)(s > th.y) << 8;
        c += (uint32_t)(s > th.z) << 16;
        c += (uint32_t)(s > th.w) << 24;
      }
      cnt[i][r] = c;
    }

  // row partials: per-row max (guarantees e >= 1), exp-sum, count; 16 independent trees
#pragma unroll
  for (int i = 0; i < 4; ++i)
#pragma unroll
    for (int r = 0; r < 4; ++r) {
      float m = fmaxf(fmaxf(acc[i][0][r], acc[i][1][r]), fmaxf(acc[i][2][r], acc[i][3][r]));
#pragma unroll
      for (int d = 1; d < 16; d <<= 1) m = fmaxf(m, __shfl_xor(m, d));
      float e = __expf(acc[i][0][r] - m) + __expf(acc[i][1][r] - m)
              + __expf(acc[i][2][r] - m) + __expf(acc[i][3][r] - m);
      uint32_t c = cnt[i][r];
#pragma unroll
      for (int d = 1; d < 16; d <<= 1) { e += __shfl_xor(e, d); c += __shfl_xor(c, d); }
      if (nl == 0) {
        int row = wr0 + i * 16 + quad * 4 + r;
        rowM[w & 1][row] = m; rowE[w & 1][row] = e; rowC[w & 1][row] = c;
      }
    }

  // col partials: per-col max, exp-sum
#pragma unroll
  for (int j = 0; j < 4; ++j) {
    float m = -3.0e38f;
#pragma unroll
    for (int i = 0; i < 4; ++i)
#pragma unroll
      for (int r = 0; r < 4; ++r) m = fmaxf(m, acc[i][j][r]);
    m = fmaxf(m, __shfl_xor(m, 16));
    m = fmaxf(m, __shfl_xor(m, 32));
    float e = 0.f;
#pragma unroll
    for (int i = 0; i < 4; ++i)
#pragma unroll
      for (int r = 0; r < 4; ++r) e += __expf(acc[i][j][r] - m);
    e += __shfl_xor(e, 16);
    e += __shfl_xor(e, 32);
    if (quad == 0) {
      int col = wc0 + j * 16 + nl;
      colM[w >> 1][col] = m; colE[w >> 1][col] = e;
    }
  }
  __syncthreads();

  // combine the two halves (online-LSE merge), coalesced [part][global-idx] writes
  if (tid < 128) {
    float M0 = rowM[0][tid], M1 = rowM[1][tid];
    float Mx = fmaxf(M0, M1);
    float Sx = rowE[0][tid] * __expf(M0 - Mx) + rowE[1][tid] * __expf(M1 - Mx);
    uint32_t C = rowC[0][tid] + rowC[1][tid];
    size_t gi = (size_t)ct * N_V + row0 + tid;
    pmax[gi] = Mx; psum[gi] = Sx; pcnt[gi] = C;
  } else {
    int c = tid - 128;
    float M0 = colM[0][c], M1 = colM[1][c];
    float Mx = fmaxf(M0, M1);
    float Sx = colE[0][c] * __expf(M0 - Mx) + colE[1][c] * __expf(M1 - Mx);
    size_t gi = (size_t)rt * NT + col0 + c;
    cmax[gi] = Mx; csum[gi] = Sx;
  }
}

// ---------------- C: reduce 128 row-partials per row (coalesced, lane-owns-row) ------------
__global__ void k_rowred(const float* __restrict__ pmax, const float* __restrict__ psum,
                         const uint32_t* __restrict__ pcnt,
                         float* __restrict__ rowm, float* __restrict__ rows_,
                         uint4* __restrict__ rcnt) {
  __shared__ float Lm[4][64], Ls[4][64];
  __shared__ uint4 Lc[4][64];
  int tid = threadIdx.x, l = tid & 63, w = tid >> 6;
  int row = blockIdx.x * 64 + l;
  float M = -3.0e38f, S = 0.f;
  uint32_t c0 = 0, c1 = 0, c2 = 0, c3 = 0;
  for (int k = 0; k < 32; ++k) {
    size_t idx = (size_t)(w * 32 + k) * N_V + row;
    float m = pmax[idx], s = psum[idx];
    uint32_t cc = pcnt[idx];
    float nM = fmaxf(M, m);
    S = S * __expf(M - nM) + s * __expf(m - nM);
    M = nM;
    c0 += cc & 0xffu; c1 += (cc >> 8) & 0xffu;
    c2 += (cc >> 16) & 0xffu; c3 += cc >> 24;
  }
  Lm[w][l] = M; Ls[w][l] = S; Lc[w][l] = make_uint4(c0, c1, c2, c3);
  __syncthreads();
  if (tid < 64) {
    float Mx = Lm[0][tid], Sx = Ls[0][tid];
    uint4 C = Lc[0][tid];
#pragma unroll
    for (int ww = 1; ww < 4; ++ww) {
      float m = Lm[ww][tid], s = Ls[ww][tid];
      float nM = fmaxf(Mx, m);
      Sx = Sx * __expf(Mx - nM) + s * __expf(m - nM);
      Mx = nM;
      uint4 cc = Lc[ww][tid];
      C.x += cc.x; C.y += cc.y; C.z += cc.z; C.w += cc.w;
    }
    int r = blockIdx.x * 64 + tid;
    rowm[r] = Mx; rows_[r] = Sx; rcnt[r] = C;
  }
}

// ---------------- D: reduce 32 col-partials per column (coalesced) -------------------------
__global__ void k_colred(const float* __restrict__ cmax, const float* __restrict__ csum,
                         float* __restrict__ colm, float* __restrict__ cols) {
  __shared__ float Cm[2][128], Cs[2][128];
  int tid = threadIdx.x, c = tid & 127, h = tid >> 7;
  int col = blockIdx.x * 128 + c;
  float M = -3.0e38f, S = 0.f;
  for (int k = 0; k < 16; ++k) {
    size_t idx = (size_t)(h * 16 + k) * NT + col;
    float m = cmax[idx], s = csum[idx];
    float nM = fmaxf(M, m);
    S = S * __expf(M - nM) + s * __expf(m - nM);
    M = nM;
  }
  Cm[h][c] = M; Cs[h][c] = S;
  __syncthreads();
  if (tid < 128) {
    float M0 = Cm[0][tid], S0 = Cs[0][tid];
    float M1 = Cm[1][tid], S1 = Cs[1][tid];
    float Mx = fmaxf(M0, M1);
    float Sx = S0 * __expf(M0 - Mx) + S1 * __expf(M1 - Mx);
    int cg = blockIdx.x * 128 + tid;
    colm[cg] = Mx; cols[cg] = Sx;
  }
}

// ---------------- E: combine per row, loss + metrics, atomic means -------------------------
__global__ void k_final(const float* __restrict__ rowm, const float* __restrict__ rows_,
                        const uint4* __restrict__ rcnt, const float* __restrict__ nom,
                        const float* __restrict__ colm, const float* __restrict__ cols,
                        float* __restrict__ out) {
  int row = blockIdx.x * 256 + threadIdx.x;
  float M = rowm[row], S = rows_[row];
  float cm0 = colm[row * 4 + 0], cm1 = colm[row * 4 + 1];
  float cm2 = colm[row * 4 + 2], cm3 = colm[row * 4 + 3];
  float cs0 = cols[row * 4 + 0], cs1 = cols[row * 4 + 1];
  float cs2 = cols[row * 4 + 2], cs3 = cols[row * 4 + 3];
  float Mp = fmaxf(M, fmaxf(fmaxf(cm0, cm1), fmaxf(cm2, cm3)));
  float tot = S * __expf(M - Mp)
            + cs0 * __expf(cm0 - Mp) + cs1 * __expf(cm1 - Mp)
            + cs2 * __expf(cm2 - Mp) + cs3 * __expf(cm3 - Mp);
  float ll = (Mp + __logf(tot)) - nom[row];
  uint4 c = rcnt[row];
  float ar  = (float)(c.x + c.y + c.z + c.w) * 0.25f;
  float r1  = (float)((c.x < 1u) + (c.y < 1u) + (c.z < 1u) + (c.w < 1u)) * 0.25f;
  float r5  = (float)((c.x < 5u) + (c.y < 5u) + (c.z < 5u) + (c.w < 5u)) * 0.25f;
  float r10 = (float)((c.x < 10u) + (c.y < 10u) + (c.z < 10u) + (c.w < 10u)) * 0.25f;
  float vals[5] = {ll, r1, r5, r10, ar};
  int l = threadIdx.x & 63;
#pragma unroll
  for (int k = 0; k < 5; ++k) {
    float v = vals[k];
#pragma unroll
    for (int d = 1; d < 64; d <<= 1) v += __shfl_xor(v, d);
    if (l == 0) atomicAdd(&out[k], v * (1.0f / N_V));
  }
}

extern "C" void kernel_launch(void* const* d_in, const int* in_sizes, int n_in,
                              void* d_out, int out_size, void* d_ws, size_t ws_size,
                              hipStream_t stream) {
  const float* v = (const float*)d_in[0];
  const float* t = (const float*)d_in[1];
  char* p = (char*)d_ws;
  unsigned short* Abf = (unsigned short*)p; p += (size_t)N_V * D_K * 2;
  unsigned short* Bbf = (unsigned short*)p; p += (size_t)NT * D_K * 2;
  float* thr  = (float*)p;    p += (size_t)N_V * 4 * 4;
  float* nom  = (float*)p;    p += (size_t)N_V * 4;
  float* pmax = (float*)p;    p += (size_t)128 * N_V * 4;
  float* psum = (float*)p;    p += (size_t)128 * N_V * 4;
  uint32_t* pcnt = (uint32_t*)p; p += (size_t)128 * N_V * 4;
  float* cmaxp = (float*)p;   p += (size_t)32 * NT * 4;
  float* csump = (float*)p;   p += (size_t)32 * NT * 4;
  float* rowm = (float*)p;    p += (size_t)N_V * 4;
  float* rows_ = (float*)p;   p += (size_t)N_V * 4;
  uint4* rcnt = (uint4*)p;    p += (size_t)N_V * 16;
  float* colm = (float*)p;    p += (size_t)NT * 4;
  float* cols = (float*)p;    p += (size_t)NT * 4;
  // total ws: ~20.5 MB

  k_convert<<<(N_V * D_K / 4 + NT * D_K / 4) / 256, 256, 0, stream>>>(v, t, Abf, Bbf);
  k_thr<<<N_V, 64, 0, stream>>>(v, t, thr, nom, (float*)d_out);
  dim3 g(NT / 128, N_V / 128);
  k_gemm<<<g, 256, 0, stream>>>(Abf, Bbf, thr, pmax, psum, pcnt, cmaxp, csump);
  k_rowred<<<N_V / 64, 256, 0, stream>>>(pmax, psum, pcnt, rowm, rows_, rcnt);
  k_colred<<<NT / 128, 256, 0, stream>>>(cmaxp, csump, colm, cols);
  k_final<<<N_V / 256, 256, 0, stream>>>(rowm, rows_, rcnt, nom, colm, cols, (float*)d_out);
}